// Round 1
// baseline (11742.607 us; speedup 1.0000x reference)
//
#include <hip/hip_runtime.h>
#include <hip/hip_bf16.h>

#define T_  256
#define P_  256
#define E_  300
#define H_  256
#define M_  50000
#define C_  16384
#define MT_ 50000
#define CT_ 16384
#define D2H 512
#define D4H 1024

// ---------------- workspace layout (bytes) ----------------
#define OFF_FLAT  0ull
#define OFF_FINAL (OFF_FLAT  + (size_t)T_*P_*D2H*2)    // flat bf16 [T*P][512]
#define OFF_PPOOL (OFF_FINAL + (size_t)CT_*D2H*4)      // final fp32 [CT][512]
#define OFF_TPOOL (OFF_PPOOL + (size_t)3*C_*D2H*4)     // pair pooled keys/pv [3][C][512]
#define OFF_H     (OFF_TPOOL + (size_t)C_*D2H*4)       // tri pooled keys/trv [C][512]
#define OFF_C     (OFF_H     + (size_t)2*2*P_*H_*4)    // h double buffer [2][2][P][H]
#define OFF_CNT   (OFF_C     + (size_t)2*P_*H_*4)      // c state [2][P][H]
#define WS_NEED   (OFF_CNT   + (size_t)4*C_*4)         // counts [4][C]
#define ZERO_BYTES (WS_NEED - OFF_PPOOL)

__device__ __forceinline__ float bf2f(unsigned short u) {
    return __uint_as_float(((unsigned)u) << 16);
}
// monotone float<->uint mapping for atomicMax on floats
__device__ __forceinline__ unsigned fmap(float f) {
    unsigned u = __float_as_uint(f);
    return (u & 0x80000000u) ? ~u : (u | 0x80000000u);
}
__device__ __forceinline__ float funmap(unsigned k) {
    return __uint_as_float((k & 0x80000000u) ? (k ^ 0x80000000u) : ~k);
}
__device__ __forceinline__ float sigmoidf_(float x) { return 1.f / (1.f + __expf(-x)); }

// ---------------- LSTM: one step, both directions ----------------
// grid: 256 blocks (dir[2] x ptile[16] x jchunk[8]), 256 threads
__global__ __launch_bounds__(256) void lstm_step_kernel(
    const float* __restrict__ x,
    const float* __restrict__ wih_f, const float* __restrict__ whh_f, const float* __restrict__ b_f,
    const float* __restrict__ wih_b, const float* __restrict__ whh_b, const float* __restrict__ b_b,
    float* __restrict__ h_buf, float* __restrict__ c_buf,
    __hip_bfloat16* __restrict__ flat, int s)
{
    const int tid = threadIdx.x;
    const int bx  = blockIdx.x;
    const int dir = bx >> 7;
    const int rem = bx & 127;
    const int p0  = (rem >> 3) << 4;   // 16 batch rows
    const int j0  = (rem & 7) << 5;    // 32 hidden cols
    const int t   = dir ? (T_ - 1 - s) : s;

    const float* wih = dir ? wih_b : wih_f;
    const float* whh = dir ? whh_b : whh_f;
    const float* bb  = dir ? b_b   : b_f;

    const int jj  = tid & 31;
    const int pg  = tid >> 5;          // 0..7
    const int pr0 = pg << 1;

    float acc[2][4] = {{0.f,0.f,0.f,0.f},{0.f,0.f,0.f,0.f}};

    __shared__ float As[16][33];
    __shared__ float Ws[32][128];      // col = gate*32 + jj

    // ---- phase 1: x[t] @ wih^T  (K = 300) ----
    const float* xt = x + (size_t)t * (P_ * E_);
    for (int kt = 0; kt < 10; ++kt) {
        const int kbase = kt << 5;
        {
            const int lp = tid >> 4;
            const int lk = (tid & 15) << 1;
            #pragma unroll
            for (int i = 0; i < 2; ++i) {
                const int k = kbase + lk + i;
                As[lp][lk + i] = (k < E_) ? xt[(size_t)(p0 + lp) * E_ + k] : 0.f;
            }
        }
        {
            const int col  = tid >> 1;
            const int grow = ((col >> 5) * H_) + j0 + (col & 31);
            const int lk0  = (tid & 1) << 4;
            const float* wrow = wih + (size_t)grow * E_;
            #pragma unroll
            for (int i = 0; i < 16; ++i) {
                const int k = kbase + lk0 + i;
                Ws[lk0 + i][col] = (k < E_) ? wrow[k] : 0.f;
            }
        }
        __syncthreads();
        #pragma unroll
        for (int kk = 0; kk < 32; ++kk) {
            const float a0 = As[pr0][kk], a1 = As[pr0 + 1][kk];
            const float w0 = Ws[kk][jj],      w1 = Ws[kk][jj + 32];
            const float w2 = Ws[kk][jj + 64], w3 = Ws[kk][jj + 96];
            acc[0][0] = fmaf(a0, w0, acc[0][0]); acc[0][1] = fmaf(a0, w1, acc[0][1]);
            acc[0][2] = fmaf(a0, w2, acc[0][2]); acc[0][3] = fmaf(a0, w3, acc[0][3]);
            acc[1][0] = fmaf(a1, w0, acc[1][0]); acc[1][1] = fmaf(a1, w1, acc[1][1]);
            acc[1][2] = fmaf(a1, w2, acc[1][2]); acc[1][3] = fmaf(a1, w3, acc[1][3]);
        }
        __syncthreads();
    }

    // ---- phase 2: h_prev @ whh^T  (K = 256) ----
    const float* hprev = h_buf + (size_t)((s & 1) * 2 + dir) * (P_ * H_);
    for (int kt = 0; kt < 8; ++kt) {
        const int kbase = kt << 5;
        {
            const int lp = tid >> 4;
            const int lk = (tid & 15) << 1;
            #pragma unroll
            for (int i = 0; i < 2; ++i)
                As[lp][lk + i] = hprev[(size_t)(p0 + lp) * H_ + kbase + lk + i];
        }
        {
            const int col  = tid >> 1;
            const int grow = ((col >> 5) * H_) + j0 + (col & 31);
            const int lk0  = (tid & 1) << 4;
            const float* wrow = whh + (size_t)grow * H_;
            #pragma unroll
            for (int i = 0; i < 16; ++i)
                Ws[lk0 + i][col] = wrow[kbase + lk0 + i];
        }
        __syncthreads();
        #pragma unroll
        for (int kk = 0; kk < 32; ++kk) {
            const float a0 = As[pr0][kk], a1 = As[pr0 + 1][kk];
            const float w0 = Ws[kk][jj],      w1 = Ws[kk][jj + 32];
            const float w2 = Ws[kk][jj + 64], w3 = Ws[kk][jj + 96];
            acc[0][0] = fmaf(a0, w0, acc[0][0]); acc[0][1] = fmaf(a0, w1, acc[0][1]);
            acc[0][2] = fmaf(a0, w2, acc[0][2]); acc[0][3] = fmaf(a0, w3, acc[0][3]);
            acc[1][0] = fmaf(a1, w0, acc[1][0]); acc[1][1] = fmaf(a1, w1, acc[1][1]);
            acc[1][2] = fmaf(a1, w2, acc[1][2]); acc[1][3] = fmaf(a1, w3, acc[1][3]);
        }
        __syncthreads();
    }

    // ---- cell update ----
    const int j = j0 + jj;
    const float bi = bb[j], bfv = bb[H_ + j], bgv = bb[2 * H_ + j], bo = bb[3 * H_ + j];
    float* hnew = h_buf + (size_t)(((s & 1) ^ 1) * 2 + dir) * (P_ * H_);
    float* cst  = c_buf + (size_t)dir * (P_ * H_);
    #pragma unroll
    for (int i = 0; i < 2; ++i) {
        const int p = p0 + pr0 + i;
        const float gi = acc[i][0] + bi;
        const float gf = acc[i][1] + bfv;
        const float gg = acc[i][2] + bgv;
        const float go = acc[i][3] + bo;
        const size_t off = (size_t)p * H_ + j;
        const float cold = cst[off];
        const float cn = sigmoidf_(gf) * cold + sigmoidf_(gi) * tanhf(gg);
        const float hn = sigmoidf_(go) * tanhf(cn);
        cst[off]  = cn;
        hnew[off] = hn;
        flat[((size_t)t * P_ + p) * D2H + dir * H_ + j] = __float2bfloat16(hn);
    }
}

// ---------------- pair GEMM + fused segment-max ----------------
// grid: (ceil(M/32), 4, 3), 256 threads; tile 32(m) x 128(n), K=1024
__global__ __launch_bounds__(256) void pair_gemm_kernel(
    const __hip_bfloat16* __restrict__ flat,
    const float* __restrict__ hW,   // [3][1024][512]
    const float* __restrict__ hb,   // [3][512]
    const int* __restrict__ occ1, const int* __restrict__ occ2,
    const int* __restrict__ seg,
    unsigned* __restrict__ pooled)  // [3][C][512] mapped keys
{
    const int type = blockIdx.z;
    const int m0 = blockIdx.x << 5;
    const int n0 = blockIdx.y << 7;
    const int tid = threadIdx.x;
    const int tm4 = (tid >> 5) << 2;
    const int tn4 = (tid & 31) << 2;
    const int* o1 = occ1 + type * M_;
    const int* o2 = occ2 + type * M_;
    const float* W = hW + (size_t)type * (D4H * D2H);

    __shared__ float As[32][33];
    __shared__ float Bs[32][128];

    float acc[4][4] = {{0,0,0,0},{0,0,0,0},{0,0,0,0},{0,0,0,0}};
    const int lm = tid >> 3;
    const int lq = (tid & 7) << 2;

    for (int kt = 0; kt < 32; ++kt) {
        {
            const int r = m0 + lm;
            float a0 = 0.f, a1 = 0.f, a2 = 0.f, a3 = 0.f;
            if (r < M_) {
                const int src = (kt < 16) ? o1[r] : o2[r];
                const int cb  = ((kt & 15) << 5) + lq;
                const ushort4 u = *(const ushort4*)((const unsigned short*)flat + (size_t)src * D2H + cb);
                a0 = bf2f(u.x); a1 = bf2f(u.y); a2 = bf2f(u.z); a3 = bf2f(u.w);
            }
            As[lm][lq + 0] = a0; As[lm][lq + 1] = a1; As[lm][lq + 2] = a2; As[lm][lq + 3] = a3;
        }
        {
            const float* Wk = W + (size_t)(kt << 5) * D2H + n0;
            #pragma unroll
            for (int i = 0; i < 4; ++i) {
                const int idx = (i << 8) + tid;
                const int kk = idx >> 5;
                const int nn = (idx & 31) << 2;
                *(float4*)&Bs[kk][nn] = *(const float4*)&Wk[(size_t)kk * D2H + nn];
            }
        }
        __syncthreads();
        #pragma unroll
        for (int kk = 0; kk < 32; ++kk) {
            const float4 bv = *(const float4*)&Bs[kk][tn4];
            #pragma unroll
            for (int i = 0; i < 4; ++i) {
                const float a = As[tm4 + i][kk];
                acc[i][0] = fmaf(a, bv.x, acc[i][0]);
                acc[i][1] = fmaf(a, bv.y, acc[i][1]);
                acc[i][2] = fmaf(a, bv.z, acc[i][2]);
                acc[i][3] = fmaf(a, bv.w, acc[i][3]);
            }
        }
        __syncthreads();
    }

    float bias[4];
    #pragma unroll
    for (int jn = 0; jn < 4; ++jn) bias[jn] = hb[type * D2H + n0 + tn4 + jn];
    #pragma unroll
    for (int i = 0; i < 4; ++i) {
        const int r = m0 + tm4 + i;
        if (r >= M_) continue;
        const int sg = seg[type * M_ + r];
        unsigned* dst = pooled + ((size_t)type * C_ + sg) * D2H + n0 + tn4;
        #pragma unroll
        for (int jn = 0; jn < 4; ++jn)
            atomicMax(dst + jn, fmap(acc[i][jn] + bias[jn]));
    }
}

// ---------------- triple GEMM + fused segment-max ----------------
// grid: (ceil(MT/32), 4), K=1536
__global__ __launch_bounds__(256) void tri_gemm_kernel(
    const __hip_bfloat16* __restrict__ flat,
    const float* __restrict__ W,    // [1536][512]
    const float* __restrict__ hb,   // [512]
    const int* __restrict__ o1, const int* __restrict__ o2, const int* __restrict__ o3,
    const int* __restrict__ seg,
    unsigned* __restrict__ pooled)  // [CT][512]
{
    const int m0 = blockIdx.x << 5;
    const int n0 = blockIdx.y << 7;
    const int tid = threadIdx.x;
    const int tm4 = (tid >> 5) << 2;
    const int tn4 = (tid & 31) << 2;

    __shared__ float As[32][33];
    __shared__ float Bs[32][128];

    float acc[4][4] = {{0,0,0,0},{0,0,0,0},{0,0,0,0},{0,0,0,0}};
    const int lm = tid >> 3;
    const int lq = (tid & 7) << 2;

    for (int kt = 0; kt < 48; ++kt) {
        {
            const int r = m0 + lm;
            float a0 = 0.f, a1 = 0.f, a2 = 0.f, a3 = 0.f;
            if (r < MT_) {
                const int src = (kt < 16) ? o1[r] : (kt < 32 ? o2[r] : o3[r]);
                const int cb  = ((kt & 15) << 5) + lq;
                const ushort4 u = *(const ushort4*)((const unsigned short*)flat + (size_t)src * D2H + cb);
                a0 = bf2f(u.x); a1 = bf2f(u.y); a2 = bf2f(u.z); a3 = bf2f(u.w);
            }
            As[lm][lq + 0] = a0; As[lm][lq + 1] = a1; As[lm][lq + 2] = a2; As[lm][lq + 3] = a3;
        }
        {
            const float* Wk = W + (size_t)(kt << 5) * D2H + n0;
            #pragma unroll
            for (int i = 0; i < 4; ++i) {
                const int idx = (i << 8) + tid;
                const int kk = idx >> 5;
                const int nn = (idx & 31) << 2;
                *(float4*)&Bs[kk][nn] = *(const float4*)&Wk[(size_t)kk * D2H + nn];
            }
        }
        __syncthreads();
        #pragma unroll
        for (int kk = 0; kk < 32; ++kk) {
            const float4 bv = *(const float4*)&Bs[kk][tn4];
            #pragma unroll
            for (int i = 0; i < 4; ++i) {
                const float a = As[tm4 + i][kk];
                acc[i][0] = fmaf(a, bv.x, acc[i][0]);
                acc[i][1] = fmaf(a, bv.y, acc[i][1]);
                acc[i][2] = fmaf(a, bv.z, acc[i][2]);
                acc[i][3] = fmaf(a, bv.w, acc[i][3]);
            }
        }
        __syncthreads();
    }

    float bias[4];
    #pragma unroll
    for (int jn = 0; jn < 4; ++jn) bias[jn] = hb[n0 + tn4 + jn];
    #pragma unroll
    for (int i = 0; i < 4; ++i) {
        const int r = m0 + tm4 + i;
        if (r >= MT_) continue;
        const int sg = seg[r];
        unsigned* dst = pooled + (size_t)sg * D2H + n0 + tn4;
        #pragma unroll
        for (int jn = 0; jn < 4; ++jn)
            atomicMax(dst + jn, fmap(acc[i][jn] + bias[jn]));
    }
}

// ---------------- counts ----------------
__global__ void counts_kernel(const int* __restrict__ seg, const int* __restrict__ tri_seg,
                              int* __restrict__ counts)
{
    const int i = blockIdx.x * 256 + threadIdx.x;
    if (i < 3 * M_) {
        atomicAdd(&counts[(i / M_) * C_ + seg[i]], 1);
    } else {
        const int m = i - 3 * M_;
        if (m < MT_) atomicAdd(&counts[3 * C_ + tri_seg[m]], 1);
    }
}

// ---------------- pair finalize: unmap/backoff + tanh + logits ----------------
// one wave per (type, candidate); grid 3*C/4, 256 threads
__global__ __launch_bounds__(256) void pair_finalize_kernel(
    unsigned* __restrict__ pooled, const int* __restrict__ counts,
    const float* __restrict__ backoff, const float* __restrict__ oW,
    const float* __restrict__ ob, float* __restrict__ out)
{
    const int lane = threadIdx.x & 63;
    const int idx  = (blockIdx.x << 2) + (threadIdx.x >> 6);  // = type*C + c
    const int type = idx / C_;
    unsigned* row = pooled + (size_t)idx * D2H;
    const int cnt = counts[idx];
    float sum = 0.f;
    #pragma unroll
    for (int q = 0; q < 8; ++q) {
        const int col = (q << 6) + lane;
        const float v = (cnt > 0) ? funmap(row[col]) : backoff[type * D2H + col];
        const float pvv = tanhf(v);
        ((float*)row)[col] = pvv;
        sum += pvv * oW[type * D2H + col];
    }
    #pragma unroll
    for (int off = 32; off > 0; off >>= 1) sum += __shfl_down(sum, off);
    if (lane == 0) out[CT_ + idx] = sum + ob[type];
}

// ---------------- triple finalize ----------------
__global__ void tri_finalize_kernel(unsigned* __restrict__ tpool,
                                    const int* __restrict__ counts,
                                    const float* __restrict__ tri_backoff)
{
    const int gid = blockIdx.x * 256 + threadIdx.x;  // over CT*512
    const int c = gid >> 9, col = gid & 511;
    const float v = (counts[3 * C_ + c] > 0) ? funmap(tpool[gid]) : tri_backoff[col];
    ((float*)tpool)[gid] = tanhf(v);
}

// ---------------- final MLP GEMM ----------------
// grid (CT/32, 4), K=2048; A gathered from pv2/pv1/pv0/trv
__global__ __launch_bounds__(256) void final_gemm_kernel(
    const float* __restrict__ pv,   // [3][C][512]
    const float* __restrict__ trv,  // [CT][512]
    const float* __restrict__ all_hW, // [2048][512]
    const float* __restrict__ all_hb, // [512]
    const int* __restrict__ tpi,      // [CT][3]
    float* __restrict__ final_buf)    // [CT][512]
{
    const int m0 = blockIdx.x << 5;
    const int n0 = blockIdx.y << 7;
    const int tid = threadIdx.x;
    const int tm4 = (tid >> 5) << 2;
    const int tn4 = (tid & 31) << 2;

    __shared__ float As[32][33];
    __shared__ float Bs[32][128];

    float acc[4][4] = {{0,0,0,0},{0,0,0,0},{0,0,0,0},{0,0,0,0}};
    const int lm = tid >> 3;
    const int lq = (tid & 7) << 2;

    for (int kt = 0; kt < 64; ++kt) {
        {
            const int r = m0 + lm;
            const int selv = kt >> 4;
            const float* srcrow;
            if (selv == 0)      srcrow = pv  + ((size_t)2 * C_ + tpi[r * 3 + 0]) * D2H;
            else if (selv == 1) srcrow = pv  + ((size_t)1 * C_ + tpi[r * 3 + 1]) * D2H;
            else if (selv == 2) srcrow = pv  + ((size_t)0 * C_ + tpi[r * 3 + 2]) * D2H;
            else                srcrow = trv + (size_t)r * D2H;
            const int cb = ((kt & 15) << 5) + lq;
            const float4 v = *(const float4*)&srcrow[cb];
            As[lm][lq + 0] = v.x; As[lm][lq + 1] = v.y; As[lm][lq + 2] = v.z; As[lm][lq + 3] = v.w;
        }
        {
            const float* Wk = all_hW + (size_t)(kt << 5) * D2H + n0;
            #pragma unroll
            for (int i = 0; i < 4; ++i) {
                const int idx = (i << 8) + tid;
                const int kk = idx >> 5;
                const int nn = (idx & 31) << 2;
                *(float4*)&Bs[kk][nn] = *(const float4*)&Wk[(size_t)kk * D2H + nn];
            }
        }
        __syncthreads();
        #pragma unroll
        for (int kk = 0; kk < 32; ++kk) {
            const float4 bv = *(const float4*)&Bs[kk][tn4];
            #pragma unroll
            for (int i = 0; i < 4; ++i) {
                const float a = As[tm4 + i][kk];
                acc[i][0] = fmaf(a, bv.x, acc[i][0]);
                acc[i][1] = fmaf(a, bv.y, acc[i][1]);
                acc[i][2] = fmaf(a, bv.z, acc[i][2]);
                acc[i][3] = fmaf(a, bv.w, acc[i][3]);
            }
        }
        __syncthreads();
    }

    #pragma unroll
    for (int i = 0; i < 4; ++i) {
        const int r = m0 + tm4 + i;
        #pragma unroll
        for (int jn = 0; jn < 4; ++jn) {
            const float v = acc[i][jn] + all_hb[n0 + tn4 + jn];
            final_buf[(size_t)r * D2H + n0 + tn4 + jn] = fmaxf(v, 0.f);
        }
    }
}

// ---------------- output logits ----------------
__global__ __launch_bounds__(256) void out_logits_kernel(
    const float* __restrict__ final_buf, const float* __restrict__ out_tW,
    const float* __restrict__ out_tb, float* __restrict__ out)
{
    const int lane = threadIdx.x & 63;
    const int r = (blockIdx.x << 2) + (threadIdx.x >> 6);
    const float* row = final_buf + (size_t)r * D2H;
    float sum = 0.f;
    #pragma unroll
    for (int q = 0; q < 8; ++q) {
        const int col = (q << 6) + lane;
        sum += row[col] * out_tW[col];
    }
    #pragma unroll
    for (int off = 32; off > 0; off >>= 1) sum += __shfl_down(sum, off);
    if (lane == 0) out[r] = sum + out_tb[0];
}

extern "C" void kernel_launch(void* const* d_in, const int* in_sizes, int n_in,
                              void* d_out, int out_size, void* d_ws, size_t ws_size,
                              hipStream_t stream)
{
    const float* x        = (const float*)d_in[0];
    const float* wih_f    = (const float*)d_in[1];
    const float* whh_f    = (const float*)d_in[2];
    const float* b_f      = (const float*)d_in[3];
    const float* wih_b    = (const float*)d_in[4];
    const float* whh_b    = (const float*)d_in[5];
    const float* b_b      = (const float*)d_in[6];
    const float* pair_hW  = (const float*)d_in[7];
    const float* pair_hb  = (const float*)d_in[8];
    const float* pair_oW  = (const float*)d_in[9];
    const float* pair_ob  = (const float*)d_in[10];
    const float* pair_bo  = (const float*)d_in[11];
    const float* tri_hW   = (const float*)d_in[12];
    const float* tri_hb   = (const float*)d_in[13];
    const float* tri_bo   = (const float*)d_in[14];
    const float* all_hW   = (const float*)d_in[15];
    const float* all_hb   = (const float*)d_in[16];
    const float* out_tW   = (const float*)d_in[17];
    const float* out_tb   = (const float*)d_in[18];
    const int*   occ1     = (const int*)d_in[19];
    const int*   occ2     = (const int*)d_in[20];
    const int*   seg      = (const int*)d_in[21];
    const int*   tri_occ1 = (const int*)d_in[22];
    const int*   tri_occ2 = (const int*)d_in[23];
    const int*   tri_occ3 = (const int*)d_in[24];
    const int*   tri_seg  = (const int*)d_in[25];
    const int*   tpi      = (const int*)d_in[26];

    if (ws_size < WS_NEED) return;  // workspace too small — fail loudly (poison stays)

    char* ws = (char*)d_ws;
    __hip_bfloat16* flat = (__hip_bfloat16*)(ws + OFF_FLAT);
    float*    final_buf  = (float*)(ws + OFF_FINAL);
    unsigned* ppool      = (unsigned*)(ws + OFF_PPOOL);
    unsigned* tpool      = (unsigned*)(ws + OFF_TPOOL);
    float*    h_buf      = (float*)(ws + OFF_H);
    float*    c_buf      = (float*)(ws + OFF_C);
    int*      counts     = (int*)(ws + OFF_CNT);
    float*    out        = (float*)d_out;

    // zero pooled keys, h/c state, counts (ws is poisoned before every call)
    hipMemsetAsync(ws + OFF_PPOOL, 0, ZERO_BYTES, stream);

    // BiLSTM: 256 sequential steps, fwd+bwd fused per launch
    for (int s = 0; s < T_; ++s)
        lstm_step_kernel<<<256, 256, 0, stream>>>(x, wih_f, whh_f, b_f,
                                                  wih_b, whh_b, b_b,
                                                  h_buf, c_buf, flat, s);

    pair_gemm_kernel<<<dim3((M_ + 31) / 32, 4, 3), 256, 0, stream>>>(
        flat, pair_hW, pair_hb, occ1, occ2, seg, ppool);
    tri_gemm_kernel<<<dim3((MT_ + 31) / 32, 4), 256, 0, stream>>>(
        flat, tri_hW, tri_hb, tri_occ1, tri_occ2, tri_occ3, tri_seg, tpool);
    counts_kernel<<<(3 * M_ + MT_ + 255) / 256, 256, 0, stream>>>(seg, tri_seg, counts);

    pair_finalize_kernel<<<(3 * C_) / 4, 256, 0, stream>>>(
        ppool, counts, pair_bo, pair_oW, pair_ob, out);
    tri_finalize_kernel<<<(CT_ * D2H) / 256, 256, 0, stream>>>(tpool, counts, tri_bo);

    final_gemm_kernel<<<dim3(CT_ / 32, 4), 256, 0, stream>>>(
        (const float*)ppool, (const float*)tpool, all_hW, all_hb, tpi, final_buf);
    out_logits_kernel<<<CT_ / 4, 256, 0, stream>>>(final_buf, out_tW, out_tb, out);
}

// Round 3
// 9027.756 us; speedup vs baseline: 1.3007x; 1.3007x over previous
//
#include <hip/hip_runtime.h>
#include <hip/hip_bf16.h>

#define T_  256
#define P_  256
#define E_  300
#define H_  256
#define M_  50000
#define C_  16384
#define MT_ 50000
#define CT_ 16384
#define D2H 512
#define D4H 1024
#define KCH 128   // K-chunk staged in LDS for MFMA GEMMs

// ---------------- workspace layout (bytes) ----------------
#define OFF_FLAT  0ull
#define OFF_PPOOL (OFF_FLAT  + (size_t)T_*P_*D2H*2)     // flat bf16 [T*P][512]
#define OFF_TPOOL (OFF_PPOOL + (size_t)3*C_*D2H*4)      // pair pooled keys/pv [3][C][512]
#define OFF_H     (OFF_TPOOL + (size_t)C_*D2H*4)        // tri pooled keys/trv [C][512]
#define OFF_C     (OFF_H     + (size_t)2*2*P_*H_*4)     // h double buffer [2][2][P][H]
#define OFF_CNT   (OFF_C     + (size_t)2*P_*H_*4)       // c state [2][P][H]
#define OFF_PWT   (OFF_CNT   + (size_t)4*C_*4)          // pair W^T bf16 [3][512][1024]
#define OFF_TWT   (OFF_PWT   + (size_t)3*D2H*D4H*2)     // tri W^T bf16 [512][1536]
#define OFF_AWT   (OFF_TWT   + (size_t)D2H*1536*2)      // all W^T bf16 [512][2048]
#define WS_NEED   (OFF_AWT   + (size_t)D2H*2048*2)
#define ZERO_BYTES (OFF_PWT - OFF_PPOOL)

typedef __attribute__((ext_vector_type(8))) short short8;
typedef __attribute__((ext_vector_type(4))) float floatx4;

__device__ __forceinline__ float bf2f(unsigned short u) {
    return __uint_as_float(((unsigned)u) << 16);
}
__device__ __forceinline__ unsigned short f2bf_rne(float f) {
    unsigned u = __float_as_uint(f);
    unsigned r = u + 0x7FFFu + ((u >> 16) & 1u);
    return (unsigned short)(r >> 16);
}
// monotone float<->uint mapping for atomicMax on floats
__device__ __forceinline__ unsigned fmap(float f) {
    unsigned u = __float_as_uint(f);
    return (u & 0x80000000u) ? ~u : (u | 0x80000000u);
}
__device__ __forceinline__ float funmap(unsigned k) {
    return __uint_as_float((k & 0x80000000u) ? (k ^ 0x80000000u) : ~k);
}
__device__ __forceinline__ float sigmoidf_(float x) { return 1.f / (1.f + __expf(-x)); }

// ---------------- weight transpose fp32 [K][N] -> bf16 [N][K] ----------------
__global__ __launch_bounds__(256) void transpose_bf16_kernel(
    const float* __restrict__ src, unsigned short* __restrict__ dst, int K, int N)
{
    __shared__ float tile[32][33];
    const int n0 = blockIdx.x << 5;
    const int k0 = blockIdx.y << 5;
    const int tx = threadIdx.x & 31;
    const int ty = threadIdx.x >> 5;   // 0..7
    #pragma unroll
    for (int i = 0; i < 4; ++i)
        tile[ty + (i << 3)][tx] = src[(size_t)(k0 + ty + (i << 3)) * N + n0 + tx];
    __syncthreads();
    #pragma unroll
    for (int i = 0; i < 4; ++i)
        dst[(size_t)(n0 + ty + (i << 3)) * K + k0 + tx] = f2bf_rne(tile[tx][ty + (i << 3)]);
}

// ---------------- LSTM: one step, both directions ----------------
__global__ __launch_bounds__(256) void lstm_step_kernel(
    const float* __restrict__ x,
    const float* __restrict__ wih_f, const float* __restrict__ whh_f, const float* __restrict__ b_f,
    const float* __restrict__ wih_b, const float* __restrict__ whh_b, const float* __restrict__ b_b,
    float* __restrict__ h_buf, float* __restrict__ c_buf,
    __hip_bfloat16* __restrict__ flat, int s)
{
    const int tid = threadIdx.x;
    const int bx  = blockIdx.x;
    const int dir = bx >> 7;
    const int rem = bx & 127;
    const int p0  = (rem >> 3) << 4;
    const int j0  = (rem & 7) << 5;
    const int t   = dir ? (T_ - 1 - s) : s;

    const float* wih = dir ? wih_b : wih_f;
    const float* whh = dir ? whh_b : whh_f;
    const float* bb  = dir ? b_b   : b_f;

    const int jj  = tid & 31;
    const int pg  = tid >> 5;
    const int pr0 = pg << 1;

    float acc[2][4] = {{0.f,0.f,0.f,0.f},{0.f,0.f,0.f,0.f}};

    __shared__ float As[16][33];
    __shared__ float Ws[32][128];

    const float* xt = x + (size_t)t * (P_ * E_);
    for (int kt = 0; kt < 10; ++kt) {
        const int kbase = kt << 5;
        {
            const int lp = tid >> 4;
            const int lk = (tid & 15) << 1;
            #pragma unroll
            for (int i = 0; i < 2; ++i) {
                const int k = kbase + lk + i;
                As[lp][lk + i] = (k < E_) ? xt[(size_t)(p0 + lp) * E_ + k] : 0.f;
            }
        }
        {
            const int col  = tid >> 1;
            const int grow = ((col >> 5) * H_) + j0 + (col & 31);
            const int lk0  = (tid & 1) << 4;
            const float* wrow = wih + (size_t)grow * E_;
            #pragma unroll
            for (int i = 0; i < 16; ++i) {
                const int k = kbase + lk0 + i;
                Ws[lk0 + i][col] = (k < E_) ? wrow[k] : 0.f;
            }
        }
        __syncthreads();
        #pragma unroll
        for (int kk = 0; kk < 32; ++kk) {
            const float a0 = As[pr0][kk], a1 = As[pr0 + 1][kk];
            const float w0 = Ws[kk][jj],      w1 = Ws[kk][jj + 32];
            const float w2 = Ws[kk][jj + 64], w3 = Ws[kk][jj + 96];
            acc[0][0] = fmaf(a0, w0, acc[0][0]); acc[0][1] = fmaf(a0, w1, acc[0][1]);
            acc[0][2] = fmaf(a0, w2, acc[0][2]); acc[0][3] = fmaf(a0, w3, acc[0][3]);
            acc[1][0] = fmaf(a1, w0, acc[1][0]); acc[1][1] = fmaf(a1, w1, acc[1][1]);
            acc[1][2] = fmaf(a1, w2, acc[1][2]); acc[1][3] = fmaf(a1, w3, acc[1][3]);
        }
        __syncthreads();
    }

    const float* hprev = h_buf + (size_t)((s & 1) * 2 + dir) * (P_ * H_);
    for (int kt = 0; kt < 8; ++kt) {
        const int kbase = kt << 5;
        {
            const int lp = tid >> 4;
            const int lk = (tid & 15) << 1;
            #pragma unroll
            for (int i = 0; i < 2; ++i)
                As[lp][lk + i] = hprev[(size_t)(p0 + lp) * H_ + kbase + lk + i];
        }
        {
            const int col  = tid >> 1;
            const int grow = ((col >> 5) * H_) + j0 + (col & 31);
            const int lk0  = (tid & 1) << 4;
            const float* wrow = whh + (size_t)grow * H_;
            #pragma unroll
            for (int i = 0; i < 16; ++i)
                Ws[lk0 + i][col] = wrow[kbase + lk0 + i];
        }
        __syncthreads();
        #pragma unroll
        for (int kk = 0; kk < 32; ++kk) {
            const float a0 = As[pr0][kk], a1 = As[pr0 + 1][kk];
            const float w0 = Ws[kk][jj],      w1 = Ws[kk][jj + 32];
            const float w2 = Ws[kk][jj + 64], w3 = Ws[kk][jj + 96];
            acc[0][0] = fmaf(a0, w0, acc[0][0]); acc[0][1] = fmaf(a0, w1, acc[0][1]);
            acc[0][2] = fmaf(a0, w2, acc[0][2]); acc[0][3] = fmaf(a0, w3, acc[0][3]);
            acc[1][0] = fmaf(a1, w0, acc[1][0]); acc[1][1] = fmaf(a1, w1, acc[1][1]);
            acc[1][2] = fmaf(a1, w2, acc[1][2]); acc[1][3] = fmaf(a1, w3, acc[1][3]);
        }
        __syncthreads();
    }

    const int j = j0 + jj;
    const float bi = bb[j], bfv = bb[H_ + j], bgv = bb[2 * H_ + j], bo = bb[3 * H_ + j];
    float* hnew = h_buf + (size_t)(((s & 1) ^ 1) * 2 + dir) * (P_ * H_);
    float* cst  = c_buf + (size_t)dir * (P_ * H_);
    #pragma unroll
    for (int i = 0; i < 2; ++i) {
        const int p = p0 + pr0 + i;
        const float gi = acc[i][0] + bi;
        const float gf = acc[i][1] + bfv;
        const float gg = acc[i][2] + bgv;
        const float go = acc[i][3] + bo;
        const size_t off = (size_t)p * H_ + j;
        const float cold = cst[off];
        const float cn = sigmoidf_(gf) * cold + sigmoidf_(gi) * tanhf(gg);
        const float hn = sigmoidf_(go) * tanhf(cn);
        cst[off]  = cn;
        hnew[off] = hn;
        flat[((size_t)t * P_ + p) * D2H + dir * H_ + j] = __float2bfloat16(hn);
    }
}

// ---------------- pair MFMA GEMM + fused segment-max ----------------
// tile M=32 x N=512; 4 waves, each wave n-strip of 128; K=1024
__global__ __launch_bounds__(256) void pair_mfma_kernel(
    const unsigned short* __restrict__ flat,
    const unsigned short* __restrict__ Wt,   // [3][512][1024] bf16
    const float* __restrict__ hb,
    const int* __restrict__ occ1, const int* __restrict__ occ2,
    const int* __restrict__ seg,
    unsigned* __restrict__ pooled)
{
    const int type = blockIdx.z;
    const int m0 = blockIdx.x << 5;
    const int tid = threadIdx.x;
    const int wave = tid >> 6, lane = tid & 63;
    const int n0w = wave << 7;
    const int lrow = lane & 15, lk = lane >> 4;

    const unsigned short* W = Wt + (size_t)type * D2H * D4H;

    __shared__ unsigned short At[32][KCH + 8];

    floatx4 acc[2][8] = {};

    const int srow = tid >> 3;
    const int scol = (tid & 7) << 4;
    const int r = m0 + srow;
    const bool rv = (r < M_);
    const int i1 = rv ? occ1[type * M_ + r] : 0;
    const int i2 = rv ? occ2[type * M_ + r] : 0;

    for (int kc = 0; kc < D4H / KCH; ++kc) {
        {
            const int kg  = kc * KCH + scol;
            const int src = (kg < 512) ? i1 : i2;
            const int col = kg & 511;
            const unsigned short* p = flat + (size_t)src * D2H + col;
            *(uint4*)&At[srow][scol]     = *(const uint4*)p;
            *(uint4*)&At[srow][scol + 8] = *(const uint4*)(p + 8);
        }
        __syncthreads();
        #pragma unroll
        for (int ks = 0; ks < KCH / 32; ++ks) {
            short8 af0 = *(const short8*)&At[lrow]     [(ks << 5) + (lk << 3)];
            short8 af1 = *(const short8*)&At[16 + lrow][(ks << 5) + (lk << 3)];
            const int kgb = kc * KCH + (ks << 5) + (lk << 3);
            const unsigned short* wb = W + (size_t)(n0w + lrow) * D4H + kgb;
            #pragma unroll
            for (int f = 0; f < 8; ++f) {
                short8 bf = *(const short8*)(wb + (size_t)(f << 4) * D4H);
                acc[0][f] = __builtin_amdgcn_mfma_f32_16x16x32_bf16(af0, bf, acc[0][f], 0, 0, 0);
                acc[1][f] = __builtin_amdgcn_mfma_f32_16x16x32_bf16(af1, bf, acc[1][f], 0, 0, 0);
            }
        }
        __syncthreads();
    }

    // epilogue: bias + atomicMax into pooled[type][seg][col]
    int   segs[2][4];
    #pragma unroll
    for (int i = 0; i < 2; ++i)
        #pragma unroll
        for (int q = 0; q < 4; ++q) {
            const int row = m0 + (i << 4) + (lk << 2) + q;
            segs[i][q] = (row < M_) ? seg[type * M_ + row] : -1;
        }
    #pragma unroll
    for (int f = 0; f < 8; ++f) {
        const int col = n0w + (f << 4) + lrow;
        const float bias = hb[type * D2H + col];
        #pragma unroll
        for (int i = 0; i < 2; ++i)
            #pragma unroll
            for (int q = 0; q < 4; ++q) {
                if (segs[i][q] < 0) continue;
                atomicMax(pooled + ((size_t)type * C_ + segs[i][q]) * D2H + col,
                          fmap(acc[i][f][q] + bias));
            }
    }
}

// ---------------- triple MFMA GEMM + fused segment-max (K=1536) ----------------
__global__ __launch_bounds__(256) void tri_mfma_kernel(
    const unsigned short* __restrict__ flat,
    const unsigned short* __restrict__ Wt,   // [512][1536]
    const float* __restrict__ hb,
    const int* __restrict__ o1, const int* __restrict__ o2, const int* __restrict__ o3,
    const int* __restrict__ seg,
    unsigned* __restrict__ pooled)
{
    const int m0 = blockIdx.x << 5;
    const int tid = threadIdx.x;
    const int wave = tid >> 6, lane = tid & 63;
    const int n0w = wave << 7;
    const int lrow = lane & 15, lk = lane >> 4;
    const int K = 1536;

    __shared__ unsigned short At[32][KCH + 8];
    floatx4 acc[2][8] = {};

    const int srow = tid >> 3;
    const int scol = (tid & 7) << 4;
    const int r = m0 + srow;
    const bool rv = (r < MT_);
    const int i1 = rv ? o1[r] : 0;
    const int i2 = rv ? o2[r] : 0;
    const int i3 = rv ? o3[r] : 0;

    for (int kc = 0; kc < 12; ++kc) {
        {
            const int kg  = kc * KCH + scol;
            const int src = (kg < 512) ? i1 : (kg < 1024 ? i2 : i3);
            const int col = kg & 511;
            const unsigned short* p = flat + (size_t)src * D2H + col;
            *(uint4*)&At[srow][scol]     = *(const uint4*)p;
            *(uint4*)&At[srow][scol + 8] = *(const uint4*)(p + 8);
        }
        __syncthreads();
        #pragma unroll
        for (int ks = 0; ks < KCH / 32; ++ks) {
            short8 af0 = *(const short8*)&At[lrow]     [(ks << 5) + (lk << 3)];
            short8 af1 = *(const short8*)&At[16 + lrow][(ks << 5) + (lk << 3)];
            const int kgb = kc * KCH + (ks << 5) + (lk << 3);
            const unsigned short* wb = Wt + (size_t)(n0w + lrow) * K + kgb;
            #pragma unroll
            for (int f = 0; f < 8; ++f) {
                short8 bf = *(const short8*)(wb + (size_t)(f << 4) * K);
                acc[0][f] = __builtin_amdgcn_mfma_f32_16x16x32_bf16(af0, bf, acc[0][f], 0, 0, 0);
                acc[1][f] = __builtin_amdgcn_mfma_f32_16x16x32_bf16(af1, bf, acc[1][f], 0, 0, 0);
            }
        }
        __syncthreads();
    }

    int segs[2][4];
    #pragma unroll
    for (int i = 0; i < 2; ++i)
        #pragma unroll
        for (int q = 0; q < 4; ++q) {
            const int row = m0 + (i << 4) + (lk << 2) + q;
            segs[i][q] = (row < MT_) ? seg[row] : -1;
        }
    #pragma unroll
    for (int f = 0; f < 8; ++f) {
        const int col = n0w + (f << 4) + lrow;
        const float bias = hb[col];
        #pragma unroll
        for (int i = 0; i < 2; ++i)
            #pragma unroll
            for (int q = 0; q < 4; ++q) {
                if (segs[i][q] < 0) continue;
                atomicMax(pooled + (size_t)segs[i][q] * D2H + col,
                          fmap(acc[i][f][q] + bias));
            }
    }
}

// ---------------- counts ----------------
__global__ void counts_kernel(const int* __restrict__ seg, const int* __restrict__ tri_seg,
                              int* __restrict__ counts)
{
    const int i = blockIdx.x * 256 + threadIdx.x;
    if (i < 3 * M_) {
        atomicAdd(&counts[(i / M_) * C_ + seg[i]], 1);
    } else {
        const int m = i - 3 * M_;
        if (m < MT_) atomicAdd(&counts[3 * C_ + tri_seg[m]], 1);
    }
}

// ---------------- pair finalize: unmap/backoff + tanh + logits ----------------
__global__ __launch_bounds__(256) void pair_finalize_kernel(
    unsigned* __restrict__ pooled, const int* __restrict__ counts,
    const float* __restrict__ backoff, const float* __restrict__ oW,
    const float* __restrict__ ob, float* __restrict__ out)
{
    const int lane = threadIdx.x & 63;
    const int idx  = (blockIdx.x << 2) + (threadIdx.x >> 6);
    const int type = idx / C_;
    unsigned* row = pooled + (size_t)idx * D2H;
    const int cnt = counts[idx];
    float sum = 0.f;
    #pragma unroll
    for (int q = 0; q < 8; ++q) {
        const int col = (q << 6) + lane;
        const float v = (cnt > 0) ? funmap(row[col]) : backoff[type * D2H + col];
        const float pvv = tanhf(v);
        ((float*)row)[col] = pvv;
        sum += pvv * oW[type * D2H + col];
    }
    #pragma unroll
    for (int off = 32; off > 0; off >>= 1) sum += __shfl_down(sum, off);
    if (lane == 0) out[CT_ + idx] = sum + ob[type];
}

// ---------------- triple finalize ----------------
__global__ void tri_finalize_kernel(unsigned* __restrict__ tpool,
                                    const int* __restrict__ counts,
                                    const float* __restrict__ tri_backoff)
{
    const int gid = blockIdx.x * 256 + threadIdx.x;
    const int c = gid >> 9, col = gid & 511;
    const float v = (counts[3 * C_ + c] > 0) ? funmap(tpool[gid]) : tri_backoff[col];
    ((float*)tpool)[gid] = tanhf(v);
}

// ---------------- final MFMA GEMM fused with output logits ----------------
// A [CT x 2048] gathered fp32 -> bf16; per block 32 rows, full N=512; K=2048
__global__ __launch_bounds__(256) void final_mfma_kernel(
    const float* __restrict__ pv,     // [3][C][512] tanh'd
    const float* __restrict__ trv,    // [CT][512] tanh'd
    const unsigned short* __restrict__ Wt,  // [512][2048] bf16
    const float* __restrict__ all_hb,
    const float* __restrict__ out_tW, const float* __restrict__ out_tb,
    const int* __restrict__ tpi,
    float* __restrict__ out)
{
    const int m0 = blockIdx.x << 5;
    const int tid = threadIdx.x;
    const int wave = tid >> 6, lane = tid & 63;
    const int n0w = wave << 7;
    const int lrow = lane & 15, lk = lane >> 4;
    const int K = 2048;

    __shared__ unsigned short At[32][KCH + 8];
    __shared__ float wpart[4][32];
    floatx4 acc[2][8] = {};

    const int srow = tid >> 3;
    const int scol = (tid & 7) << 4;
    const int r = m0 + srow;
    const float* srcs[4];
    srcs[0] = pv  + ((size_t)2 * C_ + tpi[r * 3 + 0]) * D2H;
    srcs[1] = pv  + ((size_t)1 * C_ + tpi[r * 3 + 1]) * D2H;
    srcs[2] = pv  + ((size_t)0 * C_ + tpi[r * 3 + 2]) * D2H;
    srcs[3] = trv + (size_t)r * D2H;

    for (int kc = 0; kc < 16; ++kc) {
        {
            const int kg  = kc * KCH + scol;
            const float* p = srcs[kg >> 9] + (kg & 511);
            unsigned short tmp[16];
            #pragma unroll
            for (int v4 = 0; v4 < 4; ++v4) {
                const float4 fv = *(const float4*)(p + (v4 << 2));
                tmp[v4 * 4 + 0] = f2bf_rne(fv.x);
                tmp[v4 * 4 + 1] = f2bf_rne(fv.y);
                tmp[v4 * 4 + 2] = f2bf_rne(fv.z);
                tmp[v4 * 4 + 3] = f2bf_rne(fv.w);
            }
            *(uint4*)&At[srow][scol]     = *(const uint4*)&tmp[0];
            *(uint4*)&At[srow][scol + 8] = *(const uint4*)&tmp[8];
        }
        __syncthreads();
        #pragma unroll
        for (int ks = 0; ks < KCH / 32; ++ks) {
            short8 af0 = *(const short8*)&At[lrow]     [(ks << 5) + (lk << 3)];
            short8 af1 = *(const short8*)&At[16 + lrow][(ks << 5) + (lk << 3)];
            const int kgb = kc * KCH + (ks << 5) + (lk << 3);
            const unsigned short* wb = Wt + (size_t)(n0w + lrow) * K + kgb;
            #pragma unroll
            for (int f = 0; f < 8; ++f) {
                short8 bf = *(const short8*)(wb + (size_t)(f << 4) * K);
                acc[0][f] = __builtin_amdgcn_mfma_f32_16x16x32_bf16(af0, bf, acc[0][f], 0, 0, 0);
                acc[1][f] = __builtin_amdgcn_mfma_f32_16x16x32_bf16(af1, bf, acc[1][f], 0, 0, 0);
            }
        }
        __syncthreads();
    }

    // fused epilogue: relu(acc + hb) dot out_tW, reduced per row
    float psum[2][4] = {{0,0,0,0},{0,0,0,0}};
    #pragma unroll
    for (int f = 0; f < 8; ++f) {
        const int col = n0w + (f << 4) + lrow;
        const float bias = all_hb[col];
        const float w = out_tW[col];
        #pragma unroll
        for (int i = 0; i < 2; ++i)
            #pragma unroll
            for (int q = 0; q < 4; ++q)
                psum[i][q] = fmaf(fmaxf(acc[i][f][q] + bias, 0.f), w, psum[i][q]);
    }
    #pragma unroll
    for (int i = 0; i < 2; ++i)
        #pragma unroll
        for (int q = 0; q < 4; ++q) {
            float s = psum[i][q];
            s += __shfl_xor(s, 1); s += __shfl_xor(s, 2);
            s += __shfl_xor(s, 4); s += __shfl_xor(s, 8);
            if (lrow == 0) wpart[wave][(i << 4) + (lk << 2) + q] = s;
        }
    __syncthreads();
    if (tid < 32)
        out[m0 + tid] = wpart[0][tid] + wpart[1][tid] + wpart[2][tid] + wpart[3][tid]
                        + out_tb[0];
}

extern "C" void kernel_launch(void* const* d_in, const int* in_sizes, int n_in,
                              void* d_out, int out_size, void* d_ws, size_t ws_size,
                              hipStream_t stream)
{
    const float* x        = (const float*)d_in[0];
    const float* wih_f    = (const float*)d_in[1];
    const float* whh_f    = (const float*)d_in[2];
    const float* b_f      = (const float*)d_in[3];
    const float* wih_b    = (const float*)d_in[4];
    const float* whh_b    = (const float*)d_in[5];
    const float* b_b      = (const float*)d_in[6];
    const float* pair_hW  = (const float*)d_in[7];
    const float* pair_hb  = (const float*)d_in[8];
    const float* pair_oW  = (const float*)d_in[9];
    const float* pair_ob  = (const float*)d_in[10];
    const float* pair_bo  = (const float*)d_in[11];
    const float* tri_hW   = (const float*)d_in[12];
    const float* tri_hb   = (const float*)d_in[13];
    const float* tri_bo   = (const float*)d_in[14];
    const float* all_hW   = (const float*)d_in[15];
    const float* all_hb   = (const float*)d_in[16];
    const float* out_tW   = (const float*)d_in[17];
    const float* out_tb   = (const float*)d_in[18];
    const int*   occ1     = (const int*)d_in[19];
    const int*   occ2     = (const int*)d_in[20];
    const int*   seg      = (const int*)d_in[21];
    const int*   tri_occ1 = (const int*)d_in[22];
    const int*   tri_occ2 = (const int*)d_in[23];
    const int*   tri_occ3 = (const int*)d_in[24];
    const int*   tri_seg  = (const int*)d_in[25];
    const int*   tpi      = (const int*)d_in[26];

    if (ws_size < WS_NEED) return;

    char* ws = (char*)d_ws;
    __hip_bfloat16* flat = (__hip_bfloat16*)(ws + OFF_FLAT);
    unsigned* ppool      = (unsigned*)(ws + OFF_PPOOL);
    unsigned* tpool      = (unsigned*)(ws + OFF_TPOOL);
    float*    h_buf      = (float*)(ws + OFF_H);
    float*    c_buf      = (float*)(ws + OFF_C);
    int*      counts     = (int*)(ws + OFF_CNT);
    unsigned short* pwt  = (unsigned short*)(ws + OFF_PWT);
    unsigned short* twt  = (unsigned short*)(ws + OFF_TWT);
    unsigned short* awt  = (unsigned short*)(ws + OFF_AWT);
    float*    out        = (float*)d_out;

    hipMemsetAsync(ws + OFF_PPOOL, 0, ZERO_BYTES, stream);

    // weight transposes fp32 [K][N] -> bf16 [N][K]
    for (int t = 0; t < 3; ++t)
        transpose_bf16_kernel<<<dim3(D2H / 32, D4H / 32), 256, 0, stream>>>(
            pair_hW + (size_t)t * D4H * D2H, pwt + (size_t)t * D2H * D4H, D4H, D2H);
    transpose_bf16_kernel<<<dim3(D2H / 32, 1536 / 32), 256, 0, stream>>>(tri_hW, twt, 1536, D2H);
    transpose_bf16_kernel<<<dim3(D2H / 32, 2048 / 32), 256, 0, stream>>>(all_hW, awt, 2048, D2H);

    // BiLSTM: 256 sequential steps
    for (int s = 0; s < T_; ++s)
        lstm_step_kernel<<<256, 256, 0, stream>>>(x, wih_f, whh_f, b_f,
                                                  wih_b, whh_b, b_b,
                                                  h_buf, c_buf, flat, s);

    pair_mfma_kernel<<<dim3((M_ + 31) / 32, 1, 3), 256, 0, stream>>>(
        (const unsigned short*)flat, pwt, pair_hb, occ1, occ2, seg, ppool);
    tri_mfma_kernel<<<dim3((MT_ + 31) / 32), 256, 0, stream>>>(
        (const unsigned short*)flat, twt, tri_hb, tri_occ1, tri_occ2, tri_occ3, tri_seg, tpool);
    counts_kernel<<<(3 * M_ + MT_ + 255) / 256, 256, 0, stream>>>(seg, tri_seg, counts);

    pair_finalize_kernel<<<(3 * C_) / 4, 256, 0, stream>>>(
        ppool, counts, pair_bo, pair_oW, pair_ob, out);
    tri_finalize_kernel<<<(CT_ * D2H) / 256, 256, 0, stream>>>(tpool, counts, tri_bo);

    final_mfma_kernel<<<CT_ / 32, 256, 0, stream>>>(
        (const float*)ppool, (const float*)tpool, awt, all_hb, out_tW, out_tb, tpi, out);
}